// Round 3
// baseline (377.111 us; speedup 1.0000x reference)
//
#include <hip/hip_runtime.h>
#include <stdint.h>

#define B_    4
#define S_    2048
#define DM    1024
#define NH    16
#define DH    64
#define BH    (B_ * NH)    // 64
#define MROWS (B_ * S_)    // 8192
#define LOG2E 1.4426950408889634f

typedef __attribute__((ext_vector_type(8))) short short8;
typedef __attribute__((ext_vector_type(4))) float f32x4;
typedef __attribute__((ext_vector_type(16))) float f32x16;
typedef __attribute__((ext_vector_type(4))) unsigned int u32x4;

__device__ __forceinline__ unsigned short f2bf(float f) {
  unsigned int u = __float_as_uint(f);
  u = (u + 0x7FFFu + ((u >> 16) & 1u)) >> 16;
  return (unsigned short)u;
}
// round-half-up pack (PROVEN in R4)
__device__ __forceinline__ unsigned int pack_bf16(float lo, float hi) {
  unsigned int a = (__float_as_uint(lo) + 0x8000u) >> 16;
  unsigned int b = (__float_as_uint(hi) + 0x8000u) & 0xFFFF0000u;
  return a | b;
}

__device__ __forceinline__ void gll16(const void* g, const void* l) {
  __builtin_amdgcn_global_load_lds(
      (__attribute__((address_space(1))) void*)(unsigned long long)g,
      (__attribute__((address_space(3))) void*)(unsigned int)(unsigned long long)l,
      16, 0, 0);
}

// ---------------------------------------------------------------- prep
// z in [0,3]: W[z] fp32 [k][n] -> W^T bf16 [n][k].  z in [4,7]: x -> bf16.
__global__ __launch_bounds__(256) void prep_kernel(
    const float* __restrict__ x,
    const float* __restrict__ Wq, const float* __restrict__ Wk,
    const float* __restrict__ Wv, const float* __restrict__ Wo,
    unsigned short* __restrict__ xb,
    unsigned short* __restrict__ wt_qkv, unsigned short* __restrict__ wt_o) {
  __shared__ float t[32][33];
  const int z = blockIdx.z;
  if (z >= 4) {
    size_t lb = (size_t)(z - 4) * 1024 + blockIdx.y * 32 + blockIdx.x;
    size_t i = (lb * 256 + threadIdx.x) * 8;
    float4 a = *(const float4*)(x + i);
    float4 b = *(const float4*)(x + i + 4);
    short8 o;
    o[0] = (short)f2bf(a.x); o[1] = (short)f2bf(a.y);
    o[2] = (short)f2bf(a.z); o[3] = (short)f2bf(a.w);
    o[4] = (short)f2bf(b.x); o[5] = (short)f2bf(b.y);
    o[6] = (short)f2bf(b.z); o[7] = (short)f2bf(b.w);
    *(short8*)(xb + i) = o;
    return;
  }
  const float* W = z == 0 ? Wq : z == 1 ? Wk : z == 2 ? Wv : Wo;
  unsigned short* dst = z < 3 ? wt_qkv + (size_t)z * DM * DM : wt_o;
  const int nb = blockIdx.x * 32, kb = blockIdx.y * 32;
  const int tx = threadIdx.x & 31, ty = threadIdx.x >> 5;
#pragma unroll
  for (int p = 0; p < 4; ++p) {
    int r = ty + p * 8;
    t[r][tx] = W[(size_t)(kb + r) * DM + nb + tx];
  }
  __syncthreads();
#pragma unroll
  for (int p = 0; p < 4; ++p) {
    int r = ty + p * 8;
    dst[(size_t)(nb + r) * DM + kb + tx] = f2bf(t[tx][r]);
  }
}

// ---------------------------------------------------------------- GEMM core
// 32x32x16 MFMA; layouts HW-verified (m74/m101/m89).
__device__ __forceinline__ void gemm_core(const unsigned short* __restrict__ A,
                                          const unsigned short* __restrict__ Bt,
                                          int m0, int n0,
                                          unsigned short* As, unsigned short* Bs,
                                          f32x16 (&acc)[2][2]) {
  const int tid = threadIdx.x;
  const int lane = tid & 63, wave = tid >> 6;
  const int l31 = lane & 31, half = lane >> 5;
  const int wm = (wave >> 1) * 64, wn = (wave & 1) * 64;

  for (int kk = 0; kk < DM; kk += 64) {
#pragma unroll
    for (int p = 0; p < 4; ++p) {
      int idx = p * 256 + tid;
      int row = idx >> 3, ch = idx & 7;
      int sc = (ch ^ (row & 7)) << 3;
      gll16(A  + (size_t)(m0 + row) * DM + kk + sc, As + idx * 8);
      gll16(Bt + (size_t)(n0 + row) * DM + kk + sc, Bs + idx * 8);
    }
    __syncthreads();
#pragma unroll
    for (int ks = 0; ks < 4; ++ks) {   // 4 k-steps of 16
      short8 af[2], bf[2];
#pragma unroll
      for (int mi = 0; mi < 2; ++mi) {
        int row = wm + mi * 32 + l31;
        af[mi] = *(const short8*)&As[row * 64 + (((ks * 2 + half) ^ (l31 & 7)) << 3)];
      }
#pragma unroll
      for (int nj = 0; nj < 2; ++nj) {
        int row = wn + nj * 32 + l31;
        bf[nj] = *(const short8*)&Bs[row * 64 + (((ks * 2 + half) ^ (l31 & 7)) << 3)];
      }
#pragma unroll
      for (int mi = 0; mi < 2; ++mi)
#pragma unroll
        for (int nj = 0; nj < 2; ++nj)
          acc[mi][nj] = __builtin_amdgcn_mfma_f32_32x32x16_bf16(af[mi], bf[nj], acc[mi][nj], 0, 0, 0);
    }
    __syncthreads();
  }
}

// QKV projection. V is written DIRECTLY in transposed [bh][d][s] layout
// (replaces the former transpose_v kernel; epilogue index change only).
__global__ __launch_bounds__(256) void gemm_qkv_kernel(
    const unsigned short* __restrict__ xb, const unsigned short* __restrict__ wt,
    const float* __restrict__ bq, const float* __restrict__ bk, const float* __restrict__ bv,
    unsigned short* __restrict__ Qb, unsigned short* __restrict__ Kb,
    unsigned short* __restrict__ Vt) {
  __shared__ unsigned short As[128 * 64];
  __shared__ unsigned short Bs[128 * 64];
  f32x16 acc[2][2] = {};
  const int m0 = blockIdx.y * 128, n0 = blockIdx.x * 128;
  gemm_core(xb, wt, m0, n0, As, Bs, acc);

  const int tid = threadIdx.x, lane = tid & 63, wave = tid >> 6;
  const int l31 = lane & 31, half = lane >> 5;
  const int wm = (wave >> 1) * 64, wn = (wave & 1) * 64;
  const int which = n0 >> 10;
  const int nb = n0 - (which << 10);
  if (which == 2) {
    // V -> Vt[bh][d][s]
#pragma unroll
    for (int nj = 0; nj < 2; ++nj) {
      int n10 = nb + wn + nj * 32 + l31;
      float bsv = bv[n10];
      int h = n10 >> 6, d = n10 & 63;
#pragma unroll
      for (int mi = 0; mi < 2; ++mi) {
#pragma unroll
        for (int reg = 0; reg < 16; ++reg) {
          int m = m0 + wm + mi * 32 + (reg & 3) + 8 * (reg >> 2) + 4 * half;
          int b = m >> 11, s = m & 2047;
          Vt[(((size_t)(b * NH + h)) * DH + d) * S_ + s] = f2bf(acc[mi][nj][reg] + bsv);
        }
      }
    }
    return;
  }
  const float* bias = which == 0 ? bq : bk;
  unsigned short* dst = which == 0 ? Qb : Kb;
  const float scale = (which == 0) ? 0.125f * LOG2E : 1.0f;
#pragma unroll
  for (int nj = 0; nj < 2; ++nj) {
    int n10 = nb + wn + nj * 32 + l31;
    float bsv = bias[n10];
    int h = n10 >> 6, d = n10 & 63;
#pragma unroll
    for (int mi = 0; mi < 2; ++mi) {
#pragma unroll
      for (int reg = 0; reg < 16; ++reg) {
        int m = m0 + wm + mi * 32 + (reg & 3) + 8 * (reg >> 2) + 4 * half;
        int b = m >> 11, s = m & 2047;
        float v = (acc[mi][nj][reg] + bsv) * scale;
        dst[(((size_t)(b * NH + h)) * S_ + s) * DH + d] = f2bf(v);
      }
    }
  }
}

__global__ __launch_bounds__(256) void gemm_out_kernel(
    const unsigned short* __restrict__ ctx, const unsigned short* __restrict__ wto,
    const float* __restrict__ bo, float* __restrict__ out) {
  __shared__ unsigned short As[128 * 64];
  __shared__ unsigned short Bs[128 * 64];
  f32x16 acc[2][2] = {};
  const int m0 = blockIdx.y * 128, n0 = blockIdx.x * 128;
  gemm_core(ctx, wto, m0, n0, As, Bs, acc);

  const int tid = threadIdx.x, lane = tid & 63, wave = tid >> 6;
  const int l31 = lane & 31, half = lane >> 5;
  const int wm = (wave >> 1) * 64, wn = (wave & 1) * 64;
#pragma unroll
  for (int nj = 0; nj < 2; ++nj) {
    int n = n0 + wn + nj * 32 + l31;
    float bsv = bo[n];
#pragma unroll
    for (int mi = 0; mi < 2; ++mi) {
#pragma unroll
      for (int reg = 0; reg < 16; ++reg) {
        int m = m0 + wm + mi * 32 + (reg & 3) + 8 * (reg >> 2) + 4 * half;
        out[(size_t)m * DM + n] = acc[mi][nj][reg] + bsv;
      }
    }
  }
}

// ---------------------------------------------------------------- attention
// R3: same 32x32x16 structure as R2, but the P(C-layout) -> PV A-operand
// cross-half exchange uses __shfl_xor(.,32) + select instead of the bare-asm
// v_permlane32_swap_b32 (R2's only unverifiable atom; suspected convention
// mismatch). Transform (verified element-wise vs A k=half*8+j):
//   A0=pack(p0,p1) B0=pack(p4,p5):  w0 = half? xshfl(B0) : A0
//                                   w2 = half? B0        : xshfl(A0)
//   A1=pack(p2,p3) B1=pack(p6,p7):  w1 = half? xshfl(B1) : A1
//                                   w3 = half? B1        : xshfl(A1)
// (xshfl = __shfl_xor(.,32): partner half's pack, unambiguous semantics.)
// Still: MFMA instrs 64->32 vs R1, ds_bpermute 64->32, cndmask 32->32.
// K single-buffered; K[kt+1] issued after mid barrier (flies over PV);
// V[kt] issued at loop top (flies over S+softmax). Keep (256,3): R9's
// (256,5) caused spills.
__global__ __launch_bounds__(256, 3) void attn_kernel(
    const unsigned short* __restrict__ Qb, const unsigned short* __restrict__ Kb,
    const unsigned short* __restrict__ Vt, unsigned short* __restrict__ ctx) {
  __shared__ unsigned short Ks[128 * 64];  // 16 KiB
  __shared__ unsigned short Vs[64 * 128];  // 16 KiB

  const int tid = threadIdx.x, lane = tid & 63, wave = tid >> 6;
  const int l31 = lane & 31, half = lane >> 5;
  const int bh = blockIdx.x;
  const int qt = 15 - blockIdx.y;
  const int b = bh >> 4, h = bh & 15;

  const unsigned short* Qp = Qb + ((size_t)bh * S_ + qt * 128) * DH;
  const unsigned short* Kbase = Kb + (size_t)bh * S_ * DH;
  const unsigned short* Vbase = Vt + (size_t)bh * DH * S_;

  // prologue: K tile 0 -> Ks (async); Q fragments -> registers (direct)
#pragma unroll
  for (int p = 0; p < 4; ++p) {
    int idx = p * 256 + tid;
    int row = idx >> 3, ch = idx & 7;
    int sc = (ch ^ (row & 7)) << 3;
    gll16(Kbase + row * 64 + sc, Ks + idx * 8);
  }
  // Q as B-operand: col=q=wave*32+l31, k=d=ks*16+half*8+j
  short8 qf[4];
#pragma unroll
  for (int ks = 0; ks < 4; ++ks)
    qf[ks] = *(const short8*)(Qp + (wave * 32 + l31) * 64 + ks * 16 + half * 8);
  __syncthreads();  // Ks[0] resident

  f32x16 o[2] = {};   // O: col=d=jd*32+l31, row=q=(r&3)+8*(r>>2)+4*half
  f32x4 lacc = {};

  for (int kt = 0; kt <= qt; ++kt) {
    // issue V[kt] NOW; it flies during S + softmax
    const unsigned short* Vp = Vbase + kt * 128;
#pragma unroll
    for (int p = 0; p < 4; ++p) {
      int idx = p * 256 + tid;
      int row = idx >> 4, ch = idx & 15;
      int sc = (ch & 8) | ((ch ^ row) & 7);
      gll16(Vp + (size_t)row * S_ + sc * 8, Vs + idx * 8);
    }

    // S^T = K * Q^T - 8, one 32-kv tile at a time; softmax + pack in-register
    short8 pa[8];  // PV A-frags: pa[s2] covers kv s2*16..s2*16+15
#pragma unroll
    for (int t = 0; t < 4; ++t) {
      f32x16 sa;
#pragma unroll
      for (int r = 0; r < 16; ++r) sa[r] = -8.f;
      int row = t * 32 + l31;
#pragma unroll
      for (int ks = 0; ks < 4; ++ks) {
        short8 kf = *(const short8*)&Ks[row * 64 + (((ks * 2 + half) ^ (row & 7)) << 3)];
        sa = __builtin_amdgcn_mfma_f32_32x32x16_bf16(kf, qf[ks], sa, 0, 0, 0);
      }
      if (kt == qt) {  // causal mask on diagonal tile
        int ql = wave * 32 + l31;
#pragma unroll
        for (int r = 0; r < 16; ++r) {
          int kv = t * 32 + (r & 3) + 8 * (r >> 2) + 4 * half;
          if (kv > ql) sa[r] = -__builtin_inff();
        }
      }
      float p[16];
#pragma unroll
      for (int r = 0; r < 16; ++r) {
        p[r] = __builtin_amdgcn_exp2f(sa[r]);
        lacc[r & 3] += p[r];
      }
      // regs 0-7 -> chunk kv[t*32 .. +15], regs 8-15 -> chunk kv[t*32+16 .. +31]
      {
        unsigned int A0 = pack_bf16(p[0], p[1]), A1 = pack_bf16(p[2], p[3]);
        unsigned int B0 = pack_bf16(p[4], p[5]), B1 = pack_bf16(p[6], p[7]);
        unsigned int A0x = (unsigned int)__shfl_xor((int)A0, 32);
        unsigned int A1x = (unsigned int)__shfl_xor((int)A1, 32);
        unsigned int B0x = (unsigned int)__shfl_xor((int)B0, 32);
        unsigned int B1x = (unsigned int)__shfl_xor((int)B1, 32);
        u32x4 fa;
        fa[0] = half ? B0x : A0;   // w0: [kv0,1 | kv8,9]
        fa[1] = half ? B1x : A1;   // w1: [kv2,3 | kv10,11]
        fa[2] = half ? B0  : A0x;  // w2: [kv4,5 | kv12,13]
        fa[3] = half ? B1  : A1x;  // w3: [kv6,7 | kv14,15]
        pa[2 * t] = __builtin_bit_cast(short8, fa);
      }
      {
        unsigned int C0 = pack_bf16(p[8], p[9]),   C1 = pack_bf16(p[10], p[11]);
        unsigned int D0 = pack_bf16(p[12], p[13]), D1 = pack_bf16(p[14], p[15]);
        unsigned int C0x = (unsigned int)__shfl_xor((int)C0, 32);
        unsigned int C1x = (unsigned int)__shfl_xor((int)C1, 32);
        unsigned int D0x = (unsigned int)__shfl_xor((int)D0, 32);
        unsigned int D1x = (unsigned int)__shfl_xor((int)D1, 32);
        u32x4 fb;
        fb[0] = half ? D0x : C0;   // w0: [kv16,17 | kv24,25]
        fb[1] = half ? D1x : C1;   // w1: [kv18,19 | kv26,27]
        fb[2] = half ? D0  : C0x;  // w2: [kv20,21 | kv28,29]
        fb[3] = half ? D1  : C1x;  // w3: [kv22,23 | kv30,31]
        pa[2 * t + 1] = __builtin_bit_cast(short8, fb);
      }
    }

    __syncthreads();  // V[kt] resident; all waves done reading Ks

    // prefetch K[kt+1] into Ks; it flies during the PV phase below
    if (kt < qt) {
      const unsigned short* Kp = Kbase + (size_t)(kt + 1) * 128 * DH;
#pragma unroll
      for (int p = 0; p < 4; ++p) {
        int idx = p * 256 + tid;
        int row = idx >> 3, ch = idx & 7;
        int sc = (ch ^ (row & 7)) << 3;
        gll16(Kp + row * 64 + sc, Ks + idx * 8);
      }
    }

    // O += P V : A=pa (in-register), B=V from Vs
#pragma unroll
    for (int s2 = 0; s2 < 8; ++s2) {
#pragma unroll
      for (int jd = 0; jd < 2; ++jd) {
        int row = jd * 32 + l31;                 // d row in Vs
        int c = s2 * 2 + half;                   // kv chunk of 8
        short8 vf = *(const short8*)&Vs[row * 128 + (((c & 8) | ((c ^ row) & 7)) << 3)];
        o[jd] = __builtin_amdgcn_mfma_f32_32x32x16_bf16(pa[s2], vf, o[jd], 0, 0, 0);
      }
    }
    __syncthreads();  // K[kt+1] resident; Vs WAR before next iteration's V issue
  }

  // epilogue: combine halves of l, per-row rcp, write ctx
  float l = (lacc[0] + lacc[1]) + (lacc[2] + lacc[3]);
  l += __shfl_xor(l, 32);  // lane l31=q now holds full denom for q
#pragma unroll
  for (int r = 0; r < 16; ++r) {
    int qrow = (r & 3) + 8 * (r >> 2) + 4 * half;
    float lr = __shfl(l, qrow);
    float inv = __builtin_amdgcn_rcpf(lr);
    int s = qt * 128 + wave * 32 + qrow;
#pragma unroll
    for (int jd = 0; jd < 2; ++jd) {
      int d = jd * 32 + l31;
      ctx[((size_t)(b * S_ + s)) * DM + h * DH + d] = f2bf(o[jd][r] * inv);
    }
  }
}

// ---------------------------------------------------------------- launch
extern "C" void kernel_launch(void* const* d_in, const int* in_sizes, int n_in,
                              void* d_out, int out_size, void* d_ws, size_t ws_size,
                              hipStream_t stream) {
  (void)in_sizes; (void)n_in; (void)out_size; (void)ws_size;
  const float* x  = (const float*)d_in[0];
  const float* Wq = (const float*)d_in[1];
  const float* bq = (const float*)d_in[2];
  const float* Wk = (const float*)d_in[3];
  const float* bk = (const float*)d_in[4];
  const float* Wv = (const float*)d_in[5];
  const float* bv = (const float*)d_in[6];
  const float* Wo = (const float*)d_in[7];
  const float* bo = (const float*)d_in[8];
  float* out = (float*)d_out;

  char* ws = (char*)d_ws;
  size_t off = 0;
  auto carve = [&](size_t bytes) -> char* {
    char* p = ws + off;
    off += (bytes + 255) & ~(size_t)255;
    return p;
  };
  unsigned short* xb  = (unsigned short*)carve((size_t)MROWS * DM * 2);
  unsigned short* wtq = (unsigned short*)carve((size_t)3 * DM * DM * 2);
  unsigned short* wto = (unsigned short*)carve((size_t)DM * DM * 2);
  unsigned short* Qb  = (unsigned short*)carve((size_t)BH * S_ * DH * 2);
  unsigned short* Kb  = (unsigned short*)carve((size_t)BH * S_ * DH * 2);
  unsigned short* Vt  = (unsigned short*)carve((size_t)BH * S_ * DH * 2);
  unsigned short* ctx = (unsigned short*)carve((size_t)BH * S_ * DH * 2);

  prep_kernel<<<dim3(32, 32, 8), 256, 0, stream>>>(x, Wq, Wk, Wv, Wo, xb, wtq, wto);
  gemm_qkv_kernel<<<dim3(24, 64), 256, 0, stream>>>(xb, wtq, bq, bk, bv, Qb, Kb, Vt);
  attn_kernel<<<dim3(64, 16), 256, 0, stream>>>(Qb, Kb, Vt, ctx);
  gemm_out_kernel<<<dim3(8, 64), 256, 0, stream>>>(ctx, wto, bo, out);
}

// Round 4
// 270.324 us; speedup vs baseline: 1.3950x; 1.3950x over previous
//
#include <hip/hip_runtime.h>
#include <stdint.h>

#define B_    4
#define S_    2048
#define DM    1024
#define NH    16
#define DH    64
#define BH    (B_ * NH)    // 64
#define MROWS (B_ * S_)    // 8192
#define LOG2E 1.4426950408889634f

typedef __attribute__((ext_vector_type(8))) short short8;
typedef __attribute__((ext_vector_type(4))) float f32x4;
typedef __attribute__((ext_vector_type(16))) float f32x16;
typedef __attribute__((ext_vector_type(4))) unsigned int u32x4;

__device__ __forceinline__ unsigned short f2bf(float f) {
  unsigned int u = __float_as_uint(f);
  u = (u + 0x7FFFu + ((u >> 16) & 1u)) >> 16;
  return (unsigned short)u;
}
// round-half-up pack (PROVEN in R4)
__device__ __forceinline__ unsigned int pack_bf16(float lo, float hi) {
  unsigned int a = (__float_as_uint(lo) + 0x8000u) >> 16;
  unsigned int b = (__float_as_uint(hi) + 0x8000u) & 0xFFFF0000u;
  return a | b;
}

__device__ __forceinline__ void gll16(const void* g, const void* l) {
  __builtin_amdgcn_global_load_lds(
      (__attribute__((address_space(1))) void*)(unsigned long long)g,
      (__attribute__((address_space(3))) void*)(unsigned int)(unsigned long long)l,
      16, 0, 0);
}

// ---------------------------------------------------------------- prep
// z in [0,3]: W[z] fp32 [k][n] -> W^T bf16 [n][k].  z in [4,7]: x -> bf16.
__global__ __launch_bounds__(256) void prep_kernel(
    const float* __restrict__ x,
    const float* __restrict__ Wq, const float* __restrict__ Wk,
    const float* __restrict__ Wv, const float* __restrict__ Wo,
    unsigned short* __restrict__ xb,
    unsigned short* __restrict__ wt_qkv, unsigned short* __restrict__ wt_o) {
  __shared__ float t[32][33];
  const int z = blockIdx.z;
  if (z >= 4) {
    size_t lb = (size_t)(z - 4) * 1024 + blockIdx.y * 32 + blockIdx.x;
    size_t i = (lb * 256 + threadIdx.x) * 8;
    float4 a = *(const float4*)(x + i);
    float4 b = *(const float4*)(x + i + 4);
    short8 o;
    o[0] = (short)f2bf(a.x); o[1] = (short)f2bf(a.y);
    o[2] = (short)f2bf(a.z); o[3] = (short)f2bf(a.w);
    o[4] = (short)f2bf(b.x); o[5] = (short)f2bf(b.y);
    o[6] = (short)f2bf(b.z); o[7] = (short)f2bf(b.w);
    *(short8*)(xb + i) = o;
    return;
  }
  const float* W = z == 0 ? Wq : z == 1 ? Wk : z == 2 ? Wv : Wo;
  unsigned short* dst = z < 3 ? wt_qkv + (size_t)z * DM * DM : wt_o;
  const int nb = blockIdx.x * 32, kb = blockIdx.y * 32;
  const int tx = threadIdx.x & 31, ty = threadIdx.x >> 5;
#pragma unroll
  for (int p = 0; p < 4; ++p) {
    int r = ty + p * 8;
    t[r][tx] = W[(size_t)(kb + r) * DM + nb + tx];
  }
  __syncthreads();
#pragma unroll
  for (int p = 0; p < 4; ++p) {
    int r = ty + p * 8;
    dst[(size_t)(nb + r) * DM + kb + tx] = f2bf(t[tx][r]);
  }
}

// ---------------------------------------------------------------- GEMM core
// 32x32x16 MFMA; layouts HW-verified (m74/m101/m89).
__device__ __forceinline__ void gemm_core(const unsigned short* __restrict__ A,
                                          const unsigned short* __restrict__ Bt,
                                          int m0, int n0,
                                          unsigned short* As, unsigned short* Bs,
                                          f32x16 (&acc)[2][2]) {
  const int tid = threadIdx.x;
  const int lane = tid & 63, wave = tid >> 6;
  const int l31 = lane & 31, half = lane >> 5;
  const int wm = (wave >> 1) * 64, wn = (wave & 1) * 64;

  for (int kk = 0; kk < DM; kk += 64) {
#pragma unroll
    for (int p = 0; p < 4; ++p) {
      int idx = p * 256 + tid;
      int row = idx >> 3, ch = idx & 7;
      int sc = (ch ^ (row & 7)) << 3;
      gll16(A  + (size_t)(m0 + row) * DM + kk + sc, As + idx * 8);
      gll16(Bt + (size_t)(n0 + row) * DM + kk + sc, Bs + idx * 8);
    }
    __syncthreads();
#pragma unroll
    for (int ks = 0; ks < 4; ++ks) {   // 4 k-steps of 16
      short8 af[2], bf[2];
#pragma unroll
      for (int mi = 0; mi < 2; ++mi) {
        int row = wm + mi * 32 + l31;
        af[mi] = *(const short8*)&As[row * 64 + (((ks * 2 + half) ^ (l31 & 7)) << 3)];
      }
#pragma unroll
      for (int nj = 0; nj < 2; ++nj) {
        int row = wn + nj * 32 + l31;
        bf[nj] = *(const short8*)&Bs[row * 64 + (((ks * 2 + half) ^ (l31 & 7)) << 3)];
      }
#pragma unroll
      for (int mi = 0; mi < 2; ++mi)
#pragma unroll
        for (int nj = 0; nj < 2; ++nj)
          acc[mi][nj] = __builtin_amdgcn_mfma_f32_32x32x16_bf16(af[mi], bf[nj], acc[mi][nj], 0, 0, 0);
    }
    __syncthreads();
  }
}

// QKV projection. V is written DIRECTLY in transposed [bh][d][s] layout
// (replaces the former transpose_v kernel; epilogue index change only).
__global__ __launch_bounds__(256) void gemm_qkv_kernel(
    const unsigned short* __restrict__ xb, const unsigned short* __restrict__ wt,
    const float* __restrict__ bq, const float* __restrict__ bk, const float* __restrict__ bv,
    unsigned short* __restrict__ Qb, unsigned short* __restrict__ Kb,
    unsigned short* __restrict__ Vt) {
  __shared__ unsigned short As[128 * 64];
  __shared__ unsigned short Bs[128 * 64];
  f32x16 acc[2][2] = {};
  const int m0 = blockIdx.y * 128, n0 = blockIdx.x * 128;
  gemm_core(xb, wt, m0, n0, As, Bs, acc);

  const int tid = threadIdx.x, lane = tid & 63, wave = tid >> 6;
  const int l31 = lane & 31, half = lane >> 5;
  const int wm = (wave >> 1) * 64, wn = (wave & 1) * 64;
  const int which = n0 >> 10;
  const int nb = n0 - (which << 10);
  if (which == 2) {
    // V -> Vt[bh][d][s]
#pragma unroll
    for (int nj = 0; nj < 2; ++nj) {
      int n10 = nb + wn + nj * 32 + l31;
      float bsv = bv[n10];
      int h = n10 >> 6, d = n10 & 63;
#pragma unroll
      for (int mi = 0; mi < 2; ++mi) {
#pragma unroll
        for (int reg = 0; reg < 16; ++reg) {
          int m = m0 + wm + mi * 32 + (reg & 3) + 8 * (reg >> 2) + 4 * half;
          int b = m >> 11, s = m & 2047;
          Vt[(((size_t)(b * NH + h)) * DH + d) * S_ + s] = f2bf(acc[mi][nj][reg] + bsv);
        }
      }
    }
    return;
  }
  const float* bias = which == 0 ? bq : bk;
  unsigned short* dst = which == 0 ? Qb : Kb;
  const float scale = (which == 0) ? 0.125f * LOG2E : 1.0f;
#pragma unroll
  for (int nj = 0; nj < 2; ++nj) {
    int n10 = nb + wn + nj * 32 + l31;
    float bsv = bias[n10];
    int h = n10 >> 6, d = n10 & 63;
#pragma unroll
    for (int mi = 0; mi < 2; ++mi) {
#pragma unroll
      for (int reg = 0; reg < 16; ++reg) {
        int m = m0 + wm + mi * 32 + (reg & 3) + 8 * (reg >> 2) + 4 * half;
        int b = m >> 11, s = m & 2047;
        float v = (acc[mi][nj][reg] + bsv) * scale;
        dst[(((size_t)(b * NH + h)) * S_ + s) * DH + d] = f2bf(v);
      }
    }
  }
}

__global__ __launch_bounds__(256) void gemm_out_kernel(
    const unsigned short* __restrict__ ctx, const unsigned short* __restrict__ wto,
    const float* __restrict__ bo, float* __restrict__ out) {
  __shared__ unsigned short As[128 * 64];
  __shared__ unsigned short Bs[128 * 64];
  f32x16 acc[2][2] = {};
  const int m0 = blockIdx.y * 128, n0 = blockIdx.x * 128;
  gemm_core(ctx, wto, m0, n0, As, Bs, acc);

  const int tid = threadIdx.x, lane = tid & 63, wave = tid >> 6;
  const int l31 = lane & 31, half = lane >> 5;
  const int wm = (wave >> 1) * 64, wn = (wave & 1) * 64;
#pragma unroll
  for (int nj = 0; nj < 2; ++nj) {
    int n = n0 + wn + nj * 32 + l31;
    float bsv = bo[n];
#pragma unroll
    for (int mi = 0; mi < 2; ++mi) {
#pragma unroll
      for (int reg = 0; reg < 16; ++reg) {
        int m = m0 + wm + mi * 32 + (reg & 3) + 8 * (reg >> 2) + 4 * half;
        out[(size_t)m * DM + n] = acc[mi][nj][reg] + bsv;
      }
    }
  }
}

// ---------------------------------------------------------------- attention
// R4: exact R1 16x16 compute path (PROVEN numerics: S^T=K*Q^T, static-max
// softmax P=2^(s-8), Q-in-registers, ds_bpermute C->A transform), with two
// structural changes only:
//  (1) V is NOT staged in LDS. V per (b,h) is 256 KB, L2/L3-resident
//      (R1 FETCH=34MB proves cache residency); PV B-frags load DIRECT from
//      global: verified the old stage/read swizzle pair is an involution,
//      so LDS chunk read c retrieved exactly global chunk c. Direct addr =
//      Vbase + (jo*16+col)*S_ + kt*128 + (ks*4+quad)*8 (16 full 64B lines
//      per wave-load). Deletes 4 gll16 + 16 ds_read_b128 per iteration.
//  (2) K double-buffered in LDS (32 KiB) with ONE barrier per iteration:
//      K[kt+1] staged into Ks[cur^1] right after S-phase reads of Ks[cur].
//      WAR: prior readers of Ks[cur^1] (S-phase of kt-1) settled by the
//      end-of-(kt-1) barrier. RAW: end-of-kt barrier drains vmcnt(0).
// R3 failure note: 32x32 attn restructure spilled to scratch (FETCH 399MB,
// WRITE 152MB) -> 187us. Abandoned; 16x16 + bpermute is the proven shape.
// DO NOT add min-waves launch bounds beyond 3 (R9 scar: spills).
__global__ __launch_bounds__(256, 3) void attn_kernel(
    const unsigned short* __restrict__ Qb, const unsigned short* __restrict__ Kb,
    const unsigned short* __restrict__ Vt, unsigned short* __restrict__ ctx) {
  __shared__ unsigned short Ks[2][128 * 64];  // 32 KiB (dbuf)

  const int tid = threadIdx.x, lane = tid & 63, wave = tid >> 6;
  const int col = lane & 15, quad = lane >> 4;
  const int bh = blockIdx.x;
  const int qt = 15 - blockIdx.y;
  const int b = bh >> 4, h = bh & 15;

  const unsigned short* Qp = Qb + ((size_t)bh * S_ + qt * 128) * DH;
  const unsigned short* Kbase = Kb + (size_t)bh * S_ * DH;
  const unsigned short* Vbase = Vt + (size_t)bh * DH * S_;

  // prologue: K tile 0 -> Ks[0] (async); Q fragments -> registers (direct)
#pragma unroll
  for (int p = 0; p < 4; ++p) {
    int idx = p * 256 + tid;
    int row = idx >> 3, ch = idx & 7;
    int sc = (ch ^ (row & 7)) << 3;
    gll16(Kbase + row * 64 + sc, &Ks[0][0] + idx * 8);
  }
  short8 qf[2][2];  // B-operand frags: n=q=wave*32+i*16+col, k=d
#pragma unroll
  for (int i = 0; i < 2; ++i)
#pragma unroll
    for (int ksd = 0; ksd < 2; ++ksd)
      qf[i][ksd] = *(const short8*)(Qp + (wave * 32 + i * 16 + col) * 64 + ksd * 32 + quad * 8);
  __syncthreads();  // Ks[0] resident

  f32x4 o[2][4] = {};
  f32x4 lacc[2] = {};

  const int idxA = (col + ((lane & 16) << 1)) << 2;  // src lane*4: col or col+32
  const int idxB = idxA + 64;                        // +16 lanes
  const bool hij = (lane & 32) != 0;                 // dest quads 2,3 want jt=2ks+1

  for (int kt = 0; kt <= qt; ++kt) {
    const int cur = kt & 1;

    // S^T = K * Q^T - 8 : element (kv=jt*16+quad*4+r, q=wave*32+i*16+col)
    f32x4 sa[2][8];
#pragma unroll
    for (int jt = 0; jt < 8; ++jt) {
      int row = jt * 16 + col;
      short8 kf0 = *(const short8*)&Ks[cur][row * 64 + ((quad ^ (row & 7)) << 3)];
      short8 kf1 = *(const short8*)&Ks[cur][row * 64 + (((4 + quad) ^ (row & 7)) << 3)];
#pragma unroll
      for (int i = 0; i < 2; ++i) {
        f32x4 c = {-8.f, -8.f, -8.f, -8.f};
        c = __builtin_amdgcn_mfma_f32_16x16x32_bf16(kf0, qf[i][0], c, 0, 0, 0);
        c = __builtin_amdgcn_mfma_f32_16x16x32_bf16(kf1, qf[i][1], c, 0, 0, 0);
        sa[i][jt] = c;
      }
    }

    // stage K[kt+1] into the other buffer NOW; flies over softmax (and PV
    // until the first vf global-load forces an in-order vmcnt wait)
    if (kt < qt) {
      const unsigned short* Kp = Kbase + (size_t)(kt + 1) * 128 * DH;
#pragma unroll
      for (int p = 0; p < 4; ++p) {
        int idx = p * 256 + tid;
        int row = idx >> 3, ch = idx & 7;
        int sc = (ch ^ (row & 7)) << 3;
        gll16(Kp + row * 64 + sc, &Ks[cur ^ 1][0] + idx * 8);
      }
    }

    if (kt == qt) {  // causal mask on diagonal tile
#pragma unroll
      for (int i = 0; i < 2; ++i) {
        int ql = wave * 32 + i * 16 + col;
#pragma unroll
        for (int jt = 0; jt < 8; ++jt)
#pragma unroll
          for (int r = 0; r < 4; ++r)
            if (jt * 16 + quad * 4 + r > ql) sa[i][jt][r] = -__builtin_inff();
      }
    }

    // P = exp2(s); in-lane l accumulate; pack bf16 pairs (round-half-up)
    unsigned int ppk[2][8][2];
#pragma unroll
    for (int i = 0; i < 2; ++i)
#pragma unroll
      for (int jt = 0; jt < 8; ++jt) {
        f32x4 p;
#pragma unroll
        for (int c4 = 0; c4 < 4; ++c4) {
          p[c4] = __builtin_amdgcn_exp2f(sa[i][jt][c4]);
          lacc[i][c4] += p[c4];
        }
        ppk[i][jt][0] = pack_bf16(p[0], p[1]);
        ppk[i][jt][1] = pack_bf16(p[2], p[3]);
      }

    // O += P V : A-frags via ds_bpermute, V B-frags DIRECT from global (L2)
#pragma unroll
    for (int ks = 0; ks < 4; ++ks) {
      short8 vf[4];
#pragma unroll
      for (int jo = 0; jo < 4; ++jo) {
        const unsigned short* vptr =
            Vbase + (size_t)(jo * 16 + col) * S_ + kt * 128 + (ks * 4 + quad) * 8;
        vf[jo] = *(const short8*)vptr;
      }
#pragma unroll
      for (int i = 0; i < 2; ++i) {
        int p0 = (int)ppk[i][2 * ks][0], p1 = (int)ppk[i][2 * ks][1];
        int q0 = (int)ppk[i][2 * ks + 1][0], q1 = (int)ppk[i][2 * ks + 1][1];
        int a0 = __builtin_amdgcn_ds_bpermute(idxA, p0);
        int b0 = __builtin_amdgcn_ds_bpermute(idxA, q0);
        int a1 = __builtin_amdgcn_ds_bpermute(idxA, p1);
        int b1 = __builtin_amdgcn_ds_bpermute(idxA, q1);
        int a2 = __builtin_amdgcn_ds_bpermute(idxB, p0);
        int b2 = __builtin_amdgcn_ds_bpermute(idxB, q0);
        int a3 = __builtin_amdgcn_ds_bpermute(idxB, p1);
        int b3 = __builtin_amdgcn_ds_bpermute(idxB, q1);
        u32x4 uu;
        uu[0] = (unsigned)(hij ? b0 : a0);
        uu[1] = (unsigned)(hij ? b1 : a1);
        uu[2] = (unsigned)(hij ? b2 : a2);
        uu[3] = (unsigned)(hij ? b3 : a3);
        short8 af = __builtin_bit_cast(short8, uu);
#pragma unroll
        for (int jo = 0; jo < 4; ++jo)
          o[i][jo] = __builtin_amdgcn_mfma_f32_16x16x32_bf16(af, vf[jo], o[i][jo], 0, 0, 0);
      }
    }
    __syncthreads();  // drains vmcnt(0): K[kt+1] resident; WAR for next stage
  }

  // epilogue: reduce l across quads, write ctx
#pragma unroll
  for (int i = 0; i < 2; ++i) {
    float l = (lacc[i][0] + lacc[i][1]) + (lacc[i][2] + lacc[i][3]);
    l += __shfl_xor(l, 16);
    l += __shfl_xor(l, 32);
#pragma unroll
    for (int r = 0; r < 4; ++r) {
      float lr = __shfl(l, ((lane >> 4) << 2) + r);
      float inv = __builtin_amdgcn_rcpf(lr);
      int s = qt * 128 + wave * 32 + i * 16 + quad * 4 + r;
#pragma unroll
      for (int jo = 0; jo < 4; ++jo) {
        int d = jo * 16 + col;
        ctx[((size_t)(b * S_ + s)) * DM + h * DH + d] = f2bf(o[i][jo][r] * inv);
      }
    }
  }
}

// ---------------------------------------------------------------- launch
extern "C" void kernel_launch(void* const* d_in, const int* in_sizes, int n_in,
                              void* d_out, int out_size, void* d_ws, size_t ws_size,
                              hipStream_t stream) {
  (void)in_sizes; (void)n_in; (void)out_size; (void)ws_size;
  const float* x  = (const float*)d_in[0];
  const float* Wq = (const float*)d_in[1];
  const float* bq = (const float*)d_in[2];
  const float* Wk = (const float*)d_in[3];
  const float* bk = (const float*)d_in[4];
  const float* Wv = (const float*)d_in[5];
  const float* bv = (const float*)d_in[6];
  const float* Wo = (const float*)d_in[7];
  const float* bo = (const float*)d_in[8];
  float* out = (float*)d_out;

  char* ws = (char*)d_ws;
  size_t off = 0;
  auto carve = [&](size_t bytes) -> char* {
    char* p = ws + off;
    off += (bytes + 255) & ~(size_t)255;
    return p;
  };
  unsigned short* xb  = (unsigned short*)carve((size_t)MROWS * DM * 2);
  unsigned short* wtq = (unsigned short*)carve((size_t)3 * DM * DM * 2);
  unsigned short* wto = (unsigned short*)carve((size_t)DM * DM * 2);
  unsigned short* Qb  = (unsigned short*)carve((size_t)BH * S_ * DH * 2);
  unsigned short* Kb  = (unsigned short*)carve((size_t)BH * S_ * DH * 2);
  unsigned short* Vt  = (unsigned short*)carve((size_t)BH * S_ * DH * 2);
  unsigned short* ctx = (unsigned short*)carve((size_t)BH * S_ * DH * 2);

  prep_kernel<<<dim3(32, 32, 8), 256, 0, stream>>>(x, Wq, Wk, Wv, Wo, xb, wtq, wto);
  gemm_qkv_kernel<<<dim3(24, 64), 256, 0, stream>>>(xb, wtq, bq, bk, bv, Qb, Kb, Vt);
  attn_kernel<<<dim3(64, 16), 256, 0, stream>>>(Qb, Kb, Vt, ctx);
  gemm_out_kernel<<<dim3(8, 64), 256, 0, stream>>>(ctx, wto, bo, out);
}

// Round 6
// 248.987 us; speedup vs baseline: 1.5146x; 1.0857x over previous
//
#include <hip/hip_runtime.h>
#include <stdint.h>

#define B_    4
#define S_    2048
#define DM    1024
#define NH    16
#define DH    64
#define BH    (B_ * NH)    // 64
#define MROWS (B_ * S_)    // 8192
#define LOG2E 1.4426950408889634f

typedef __attribute__((ext_vector_type(8))) short short8;
typedef __attribute__((ext_vector_type(4))) float f32x4;
typedef __attribute__((ext_vector_type(16))) float f32x16;
typedef __attribute__((ext_vector_type(4))) unsigned int u32x4;

__device__ __forceinline__ unsigned short f2bf(float f) {
  unsigned int u = __float_as_uint(f);
  u = (u + 0x7FFFu + ((u >> 16) & 1u)) >> 16;
  return (unsigned short)u;
}
// round-half-up pack (PROVEN in R4)
__device__ __forceinline__ unsigned int pack_bf16(float lo, float hi) {
  unsigned int a = (__float_as_uint(lo) + 0x8000u) >> 16;
  unsigned int b = (__float_as_uint(hi) + 0x8000u) & 0xFFFF0000u;
  return a | b;
}

__device__ __forceinline__ void gll16(const void* g, const void* l) {
  __builtin_amdgcn_global_load_lds(
      (__attribute__((address_space(1))) void*)(unsigned long long)g,
      (__attribute__((address_space(3))) void*)(unsigned int)(unsigned long long)l,
      16, 0, 0);
}

// ---------------------------------------------------------------- prep
// z in [0,3]: W[z] fp32 [k][n] -> W^T bf16 [n][k].  z in [4,7]: x -> bf16.
__global__ __launch_bounds__(256) void prep_kernel(
    const float* __restrict__ x,
    const float* __restrict__ Wq, const float* __restrict__ Wk,
    const float* __restrict__ Wv, const float* __restrict__ Wo,
    unsigned short* __restrict__ xb,
    unsigned short* __restrict__ wt_qkv, unsigned short* __restrict__ wt_o) {
  __shared__ float t[32][33];
  const int z = blockIdx.z;
  if (z >= 4) {
    size_t lb = (size_t)(z - 4) * 1024 + blockIdx.y * 32 + blockIdx.x;
    size_t i = (lb * 256 + threadIdx.x) * 8;
    float4 a = *(const float4*)(x + i);
    float4 b = *(const float4*)(x + i + 4);
    short8 o;
    o[0] = (short)f2bf(a.x); o[1] = (short)f2bf(a.y);
    o[2] = (short)f2bf(a.z); o[3] = (short)f2bf(a.w);
    o[4] = (short)f2bf(b.x); o[5] = (short)f2bf(b.y);
    o[6] = (short)f2bf(b.z); o[7] = (short)f2bf(b.w);
    *(short8*)(xb + i) = o;
    return;
  }
  const float* W = z == 0 ? Wq : z == 1 ? Wk : z == 2 ? Wv : Wo;
  unsigned short* dst = z < 3 ? wt_qkv + (size_t)z * DM * DM : wt_o;
  const int nb = blockIdx.x * 32, kb = blockIdx.y * 32;
  const int tx = threadIdx.x & 31, ty = threadIdx.x >> 5;
#pragma unroll
  for (int p = 0; p < 4; ++p) {
    int r = ty + p * 8;
    t[r][tx] = W[(size_t)(kb + r) * DM + nb + tx];
  }
  __syncthreads();
#pragma unroll
  for (int p = 0; p < 4; ++p) {
    int r = ty + p * 8;
    dst[(size_t)(nb + r) * DM + kb + tx] = f2bf(t[tx][r]);
  }
}

// ---------------------------------------------------------------- GEMM core
// 32x32x16 MFMA; layouts HW-verified (m74/m101/m89).
__device__ __forceinline__ void gemm_core(const unsigned short* __restrict__ A,
                                          const unsigned short* __restrict__ Bt,
                                          int m0, int n0,
                                          unsigned short* As, unsigned short* Bs,
                                          f32x16 (&acc)[2][2]) {
  const int tid = threadIdx.x;
  const int lane = tid & 63, wave = tid >> 6;
  const int l31 = lane & 31, half = lane >> 5;
  const int wm = (wave >> 1) * 64, wn = (wave & 1) * 64;

  for (int kk = 0; kk < DM; kk += 64) {
#pragma unroll
    for (int p = 0; p < 4; ++p) {
      int idx = p * 256 + tid;
      int row = idx >> 3, ch = idx & 7;
      int sc = (ch ^ (row & 7)) << 3;
      gll16(A  + (size_t)(m0 + row) * DM + kk + sc, As + idx * 8);
      gll16(Bt + (size_t)(n0 + row) * DM + kk + sc, Bs + idx * 8);
    }
    __syncthreads();
#pragma unroll
    for (int ks = 0; ks < 4; ++ks) {   // 4 k-steps of 16
      short8 af[2], bf[2];
#pragma unroll
      for (int mi = 0; mi < 2; ++mi) {
        int row = wm + mi * 32 + l31;
        af[mi] = *(const short8*)&As[row * 64 + (((ks * 2 + half) ^ (l31 & 7)) << 3)];
      }
#pragma unroll
      for (int nj = 0; nj < 2; ++nj) {
        int row = wn + nj * 32 + l31;
        bf[nj] = *(const short8*)&Bs[row * 64 + (((ks * 2 + half) ^ (l31 & 7)) << 3)];
      }
#pragma unroll
      for (int mi = 0; mi < 2; ++mi)
#pragma unroll
        for (int nj = 0; nj < 2; ++nj)
          acc[mi][nj] = __builtin_amdgcn_mfma_f32_32x32x16_bf16(af[mi], bf[nj], acc[mi][nj], 0, 0, 0);
    }
    __syncthreads();
  }
}

// QKV projection. V is written DIRECTLY in transposed [bh][d][s] layout
// (replaces the former transpose_v kernel; epilogue index change only).
__global__ __launch_bounds__(256) void gemm_qkv_kernel(
    const unsigned short* __restrict__ xb, const unsigned short* __restrict__ wt,
    const float* __restrict__ bq, const float* __restrict__ bk, const float* __restrict__ bv,
    unsigned short* __restrict__ Qb, unsigned short* __restrict__ Kb,
    unsigned short* __restrict__ Vt) {
  __shared__ unsigned short As[128 * 64];
  __shared__ unsigned short Bs[128 * 64];
  f32x16 acc[2][2] = {};
  const int m0 = blockIdx.y * 128, n0 = blockIdx.x * 128;
  gemm_core(xb, wt, m0, n0, As, Bs, acc);

  const int tid = threadIdx.x, lane = tid & 63, wave = tid >> 6;
  const int l31 = lane & 31, half = lane >> 5;
  const int wm = (wave >> 1) * 64, wn = (wave & 1) * 64;
  const int which = n0 >> 10;
  const int nb = n0 - (which << 10);
  if (which == 2) {
    // V -> Vt[bh][d][s]
#pragma unroll
    for (int nj = 0; nj < 2; ++nj) {
      int n10 = nb + wn + nj * 32 + l31;
      float bsv = bv[n10];
      int h = n10 >> 6, d = n10 & 63;
#pragma unroll
      for (int mi = 0; mi < 2; ++mi) {
#pragma unroll
        for (int reg = 0; reg < 16; ++reg) {
          int m = m0 + wm + mi * 32 + (reg & 3) + 8 * (reg >> 2) + 4 * half;
          int b = m >> 11, s = m & 2047;
          Vt[(((size_t)(b * NH + h)) * DH + d) * S_ + s] = f2bf(acc[mi][nj][reg] + bsv);
        }
      }
    }
    return;
  }
  const float* bias = which == 0 ? bq : bk;
  unsigned short* dst = which == 0 ? Qb : Kb;
  const float scale = (which == 0) ? 0.125f * LOG2E : 1.0f;
#pragma unroll
  for (int nj = 0; nj < 2; ++nj) {
    int n10 = nb + wn + nj * 32 + l31;
    float bsv = bias[n10];
    int h = n10 >> 6, d = n10 & 63;
#pragma unroll
    for (int mi = 0; mi < 2; ++mi) {
#pragma unroll
      for (int reg = 0; reg < 16; ++reg) {
        int m = m0 + wm + mi * 32 + (reg & 3) + 8 * (reg >> 2) + 4 * half;
        int b = m >> 11, s = m & 2047;
        float v = (acc[mi][nj][reg] + bsv) * scale;
        dst[(((size_t)(b * NH + h)) * S_ + s) * DH + d] = f2bf(v);
      }
    }
  }
}

__global__ __launch_bounds__(256) void gemm_out_kernel(
    const unsigned short* __restrict__ ctx, const unsigned short* __restrict__ wto,
    const float* __restrict__ bo, float* __restrict__ out) {
  __shared__ unsigned short As[128 * 64];
  __shared__ unsigned short Bs[128 * 64];
  f32x16 acc[2][2] = {};
  const int m0 = blockIdx.y * 128, n0 = blockIdx.x * 128;
  gemm_core(ctx, wto, m0, n0, As, Bs, acc);

  const int tid = threadIdx.x, lane = tid & 63, wave = tid >> 6;
  const int l31 = lane & 31, half = lane >> 5;
  const int wm = (wave >> 1) * 64, wn = (wave & 1) * 64;
#pragma unroll
  for (int nj = 0; nj < 2; ++nj) {
    int n = n0 + wn + nj * 32 + l31;
    float bsv = bo[n];
#pragma unroll
    for (int mi = 0; mi < 2; ++mi) {
#pragma unroll
      for (int reg = 0; reg < 16; ++reg) {
        int m = m0 + wm + mi * 32 + (reg & 3) + 8 * (reg >> 2) + 4 * half;
        out[(size_t)m * DM + n] = acc[mi][nj][reg] + bsv;
      }
    }
  }
}

// ---------------------------------------------------------------- attention
// R6: R3's PASSING 32x32 numerics (shfl_xor+select transform — permlane is
// abandoned: both asm conventions failed, R2=0.033/R5=1.86), with the spill
// killed two ways:
//  (1) __launch_bounds__(256,2): raises VGPR cap to ~256. Under (256,3)
//      every attn variant pinned at VGPR_Count=84 and R3's bigger live set
//      spilled to scratch (FETCH 399MB / WRITE 152MB -> 187us).
//  (2) rule-#20-proofing: pa[8]/o[2]/lacc arrays replaced with NAMED
//      registers (pa0..pa7, o0/o1, la0..la3) via macro-expanded tiles, so
//      no runtime-indexable aggregate exists regardless of unroll decisions.
// Schedule unchanged from R3 (proven): V LDS-staged at loop top, K single-
// buffer with post-mid-barrier prefetch flying over PV.
// Pre-committed fallback: if attn >= 84us (R1 level), revert attn to R1 and
// spend remaining rounds on the 8-phase GEMM.

#define TTILE(T, PAE, PAO) do {                                              \
    f32x16 sa;                                                               \
    _Pragma("unroll") for (int r = 0; r < 16; ++r) sa[r] = -8.f;             \
    {                                                                        \
      int row = (T) * 32 + l31;                                              \
      _Pragma("unroll") for (int ks = 0; ks < 4; ++ks) {                     \
        short8 kf = *(const short8*)&Ks[row * 64 +                           \
                      (((ks * 2 + half) ^ (row & 7)) << 3)];                 \
        sa = __builtin_amdgcn_mfma_f32_32x32x16_bf16(kf, qf[ks], sa, 0, 0, 0);\
      }                                                                      \
    }                                                                        \
    if (kt == qt) {                                                          \
      int ql = wave * 32 + l31;                                              \
      _Pragma("unroll") for (int r = 0; r < 16; ++r) {                       \
        int kv = (T) * 32 + (r & 3) + 8 * (r >> 2) + 4 * half;               \
        if (kv > ql) sa[r] = -__builtin_inff();                              \
      }                                                                      \
    }                                                                        \
    float p[16];                                                             \
    _Pragma("unroll") for (int r = 0; r < 16; ++r)                           \
      p[r] = __builtin_amdgcn_exp2f(sa[r]);                                  \
    la0 += p[0] + p[4] + p[8]  + p[12];                                      \
    la1 += p[1] + p[5] + p[9]  + p[13];                                      \
    la2 += p[2] + p[6] + p[10] + p[14];                                      \
    la3 += p[3] + p[7] + p[11] + p[15];                                      \
    {                                                                        \
      unsigned int A0 = pack_bf16(p[0], p[1]), A1 = pack_bf16(p[2], p[3]);   \
      unsigned int B0 = pack_bf16(p[4], p[5]), B1 = pack_bf16(p[6], p[7]);   \
      unsigned int A0x = (unsigned int)__shfl_xor((int)A0, 32);              \
      unsigned int A1x = (unsigned int)__shfl_xor((int)A1, 32);              \
      unsigned int B0x = (unsigned int)__shfl_xor((int)B0, 32);              \
      unsigned int B1x = (unsigned int)__shfl_xor((int)B1, 32);              \
      u32x4 fa;                                                              \
      fa[0] = half ? B0x : A0;                                               \
      fa[1] = half ? B1x : A1;                                               \
      fa[2] = half ? B0  : A0x;                                              \
      fa[3] = half ? B1  : A1x;                                              \
      PAE = __builtin_bit_cast(short8, fa);                                  \
    }                                                                        \
    {                                                                        \
      unsigned int C0 = pack_bf16(p[8], p[9]),   C1 = pack_bf16(p[10], p[11]);\
      unsigned int D0 = pack_bf16(p[12], p[13]), D1 = pack_bf16(p[14], p[15]);\
      unsigned int C0x = (unsigned int)__shfl_xor((int)C0, 32);              \
      unsigned int C1x = (unsigned int)__shfl_xor((int)C1, 32);              \
      unsigned int D0x = (unsigned int)__shfl_xor((int)D0, 32);              \
      unsigned int D1x = (unsigned int)__shfl_xor((int)D1, 32);              \
      u32x4 fb;                                                              \
      fb[0] = half ? D0x : C0;                                               \
      fb[1] = half ? D1x : C1;                                               \
      fb[2] = half ? D0  : C0x;                                              \
      fb[3] = half ? D1  : C1x;                                              \
      PAO = __builtin_bit_cast(short8, fb);                                  \
    }                                                                        \
  } while (0)

#define PVSTEP(S2, PA) do {                                                  \
    int c = (S2) * 2 + half;                                                 \
    {                                                                        \
      int row = l31;                                                         \
      short8 vf = *(const short8*)&Vs[row * 128 +                            \
                    (((c & 8) | ((c ^ row) & 7)) << 3)];                     \
      o0 = __builtin_amdgcn_mfma_f32_32x32x16_bf16(PA, vf, o0, 0, 0, 0);     \
    }                                                                        \
    {                                                                        \
      int row = 32 + l31;                                                    \
      short8 vf = *(const short8*)&Vs[row * 128 +                            \
                    (((c & 8) | ((c ^ row) & 7)) << 3)];                     \
      o1 = __builtin_amdgcn_mfma_f32_32x32x16_bf16(PA, vf, o1, 0, 0, 0);     \
    }                                                                        \
  } while (0)

__global__ __launch_bounds__(256, 2) void attn_kernel(
    const unsigned short* __restrict__ Qb, const unsigned short* __restrict__ Kb,
    const unsigned short* __restrict__ Vt, unsigned short* __restrict__ ctx) {
  __shared__ unsigned short Ks[128 * 64];  // 16 KiB
  __shared__ unsigned short Vs[64 * 128];  // 16 KiB

  const int tid = threadIdx.x, lane = tid & 63, wave = tid >> 6;
  const int l31 = lane & 31, half = lane >> 5;
  const int bh = blockIdx.x;
  const int qt = 15 - blockIdx.y;
  const int b = bh >> 4, h = bh & 15;

  const unsigned short* Qp = Qb + ((size_t)bh * S_ + qt * 128) * DH;
  const unsigned short* Kbase = Kb + (size_t)bh * S_ * DH;
  const unsigned short* Vbase = Vt + (size_t)bh * DH * S_;

  // prologue: K tile 0 -> Ks (async); Q fragments -> registers (direct)
#pragma unroll
  for (int p = 0; p < 4; ++p) {
    int idx = p * 256 + tid;
    int row = idx >> 3, ch = idx & 7;
    int sc = (ch ^ (row & 7)) << 3;
    gll16(Kbase + row * 64 + sc, Ks + idx * 8);
  }
  // Q as B-operand: col=q=wave*32+l31, k=d=ks*16+half*8+j
  short8 qf[4];
#pragma unroll
  for (int ks = 0; ks < 4; ++ks)
    qf[ks] = *(const short8*)(Qp + (wave * 32 + l31) * 64 + ks * 16 + half * 8);
  __syncthreads();  // Ks[0] resident

  f32x16 o0 = {}, o1 = {};  // O: col=d=jd*32+l31, row=q=(r&3)+8*(r>>2)+4*half
  float la0 = 0.f, la1 = 0.f, la2 = 0.f, la3 = 0.f;

  for (int kt = 0; kt <= qt; ++kt) {
    // issue V[kt] NOW; it flies during S + softmax
    const unsigned short* Vp = Vbase + kt * 128;
#pragma unroll
    for (int p = 0; p < 4; ++p) {
      int idx = p * 256 + tid;
      int row = idx >> 4, ch = idx & 15;
      int sc = (ch & 8) | ((ch ^ row) & 7);
      gll16(Vp + (size_t)row * S_ + sc * 8, Vs + idx * 8);
    }

    // S^T = K * Q^T - 8, softmax + pack + cross-half exchange, all in-register
    short8 pa0, pa1, pa2, pa3, pa4, pa5, pa6, pa7;
    TTILE(0, pa0, pa1);
    TTILE(1, pa2, pa3);
    TTILE(2, pa4, pa5);
    TTILE(3, pa6, pa7);

    __syncthreads();  // V[kt] resident; all waves done reading Ks

    // prefetch K[kt+1] into Ks; it flies during the PV phase below
    if (kt < qt) {
      const unsigned short* Kp = Kbase + (size_t)(kt + 1) * 128 * DH;
#pragma unroll
      for (int p = 0; p < 4; ++p) {
        int idx = p * 256 + tid;
        int row = idx >> 3, ch = idx & 7;
        int sc = (ch ^ (row & 7)) << 3;
        gll16(Kp + row * 64 + sc, Ks + idx * 8);
      }
    }

    // O += P V : A = named pa regs, B = V from Vs
    PVSTEP(0, pa0); PVSTEP(1, pa1); PVSTEP(2, pa2); PVSTEP(3, pa3);
    PVSTEP(4, pa4); PVSTEP(5, pa5); PVSTEP(6, pa6); PVSTEP(7, pa7);

    __syncthreads();  // K[kt+1] resident; Vs WAR before next iteration's V issue
  }

  // epilogue: combine halves of l, per-row rcp, write ctx
  float l = (la0 + la1) + (la2 + la3);
  l += __shfl_xor(l, 32);  // lane l31=q now holds full denom for q
#pragma unroll
  for (int r = 0; r < 16; ++r) {
    int qrow = (r & 3) + 8 * (r >> 2) + 4 * half;
    float lr = __shfl(l, qrow);
    float inv = __builtin_amdgcn_rcpf(lr);
    int s = qt * 128 + wave * 32 + qrow;
    ctx[((size_t)(b * S_ + s)) * DM + h * DH + l31]      = f2bf(o0[r] * inv);
    ctx[((size_t)(b * S_ + s)) * DM + h * DH + 32 + l31] = f2bf(o1[r] * inv);
  }
}

// ---------------------------------------------------------------- launch
extern "C" void kernel_launch(void* const* d_in, const int* in_sizes, int n_in,
                              void* d_out, int out_size, void* d_ws, size_t ws_size,
                              hipStream_t stream) {
  (void)in_sizes; (void)n_in; (void)out_size; (void)ws_size;
  const float* x  = (const float*)d_in[0];
  const float* Wq = (const float*)d_in[1];
  const float* bq = (const float*)d_in[2];
  const float* Wk = (const float*)d_in[3];
  const float* bk = (const float*)d_in[4];
  const float* Wv = (const float*)d_in[5];
  const float* bv = (const float*)d_in[6];
  const float* Wo = (const float*)d_in[7];
  const float* bo = (const float*)d_in[8];
  float* out = (float*)d_out;

  char* ws = (char*)d_ws;
  size_t off = 0;
  auto carve = [&](size_t bytes) -> char* {
    char* p = ws + off;
    off += (bytes + 255) & ~(size_t)255;
    return p;
  };
  unsigned short* xb  = (unsigned short*)carve((size_t)MROWS * DM * 2);
  unsigned short* wtq = (unsigned short*)carve((size_t)3 * DM * DM * 2);
  unsigned short* wto = (unsigned short*)carve((size_t)DM * DM * 2);
  unsigned short* Qb  = (unsigned short*)carve((size_t)BH * S_ * DH * 2);
  unsigned short* Kb  = (unsigned short*)carve((size_t)BH * S_ * DH * 2);
  unsigned short* Vt  = (unsigned short*)carve((size_t)BH * S_ * DH * 2);
  unsigned short* ctx = (unsigned short*)carve((size_t)BH * S_ * DH * 2);

  prep_kernel<<<dim3(32, 32, 8), 256, 0, stream>>>(x, Wq, Wk, Wv, Wo, xb, wtq, wto);
  gemm_qkv_kernel<<<dim3(24, 64), 256, 0, stream>>>(xb, wtq, bq, bk, bv, Qb, Kb, Vt);
  attn_kernel<<<dim3(64, 16), 256, 0, stream>>>(Qb, Kb, Vt, ctx);
  gemm_out_kernel<<<dim3(8, 64), 256, 0, stream>>>(ctx, wto, bo, out);
}